// Round 3
// baseline (1527.038 us; speedup 1.0000x reference)
//
#include <hip/hip_runtime.h>

#define DD   64
#define GSH  7            // 128 nodes per group
#define GSZ  128
#define TILE 8192
#define GMAX 1024         // supports N <= 131072
#define AMAX 1024         // branch-a list capacity

typedef unsigned int u32;

// ---------------------------------------------------------------------------
__global__ __launch_bounds__(512)
void k_relctx(const float* __restrict__ rel, int R, float* __restrict__ ctx) {
    __shared__ float part[8][DD];
    int d = threadIdx.x & 63;
    int w = threadIdx.x >> 6;
    float s = 0.f;
    for (int r = w; r < R; r += 8) s += rel[r * DD + d];
    part[w][d] = s;
    __syncthreads();
    if (threadIdx.x < DD) {
        float t = 0.f;
        #pragma unroll
        for (int i = 0; i < 8; ++i) t += part[i][threadIdx.x];
        ctx[threadIdx.x] = t / (float)R;
    }
}

// ---------------------------------------------------------------------------
// Pass 1: incidences per 128-node group, LDS histogram per block.
__global__ __launch_bounds__(512)
void k_gcount(const int* __restrict__ src, const int* __restrict__ dst,
              int* __restrict__ gcnt, int E, int G) {
    __shared__ int lcnt[GMAX];
    for (int i = threadIdx.x; i < G; i += 512) lcnt[i] = 0;
    __syncthreads();
    int t0 = blockIdx.x * TILE;
    int t1 = min(t0 + TILE, E);
    for (int i = t0 + threadIdx.x; i < t1; i += 512) {
        int s = src[i], d = dst[i];
        atomicAdd(&lcnt[s >> GSH], 1);
        if (s != d) atomicAdd(&lcnt[d >> GSH], 1);
    }
    __syncthreads();
    for (int g = threadIdx.x; g < G; g += 512) {
        int c = lcnt[g];
        if (c) atomicAdd(&gcnt[g], c);
    }
}

// ---------------------------------------------------------------------------
__global__ __launch_bounds__(1024)
void k_scan(const int* __restrict__ gcnt, int* __restrict__ goff,
            int* __restrict__ gcur, int G) {
    __shared__ int sh[GMAX];
    int t = threadIdx.x;
    int v = (t < G) ? gcnt[t] : 0;
    sh[t] = v;
    __syncthreads();
    for (int d = 1; d < GMAX; d <<= 1) {
        int x = (t >= d) ? sh[t - d] : 0;
        __syncthreads();
        sh[t] += x;
        __syncthreads();
    }
    if (t < G) { int off = sh[t] - v; goff[t] = off; gcur[t] = off; }
    if (t == GMAX - 1) goff[G] = sh[GMAX - 1];
}

// ---------------------------------------------------------------------------
// Pass 2: place entries into coarse group streams. Per block: local histogram,
// one global reservation per touched group, then contiguous run writes.
// entry u32 = local_node(7b) | etype<<7 | self<<31
__global__ __launch_bounds__(512)
void k_gplace(const int* __restrict__ src, const int* __restrict__ dst,
              const int* __restrict__ etype, int* __restrict__ gcur,
              u32* __restrict__ es, int E, int G) {
    __shared__ int lcnt[GMAX];
    __shared__ int lbase[GMAX];
    for (int i = threadIdx.x; i < G; i += 512) lcnt[i] = 0;
    __syncthreads();
    int t0 = blockIdx.x * TILE;
    int t1 = min(t0 + TILE, E);
    for (int i = t0 + threadIdx.x; i < t1; i += 512) {
        int s = src[i], d = dst[i];
        atomicAdd(&lcnt[s >> GSH], 1);
        if (s != d) atomicAdd(&lcnt[d >> GSH], 1);
    }
    __syncthreads();
    for (int g = threadIdx.x; g < G; g += 512) {
        int c = lcnt[g];
        lbase[g] = c ? atomicAdd(&gcur[g], c) : 0;
        lcnt[g] = 0;
    }
    __syncthreads();
    for (int i = t0 + threadIdx.x; i < t1; i += 512) {
        int s = src[i], d = dst[i];
        u32 t = (u32)etype[i] << GSH;
        if (s != d) {
            int gs = s >> GSH;
            int p = atomicAdd(&lcnt[gs], 1);
            es[lbase[gs] + p] = (u32)(s & (GSZ - 1)) | t;
            int gd = d >> GSH;
            int q = atomicAdd(&lcnt[gd], 1);
            es[lbase[gd] + q] = (u32)(d & (GSZ - 1)) | t;
        } else {
            int gs = s >> GSH;
            int p = atomicAdd(&lcnt[gs], 1);
            es[lbase[gs] + p] = (u32)(s & (GSZ - 1)) | t | 0x80000000u;
        }
    }
}

// ---------------------------------------------------------------------------
// One block per 128-node group: LDS-accumulate rel rows + counts, then fused
// branch-b MLP (concat halves of w1 pre-added). All-self nodes -> alist+wsf.
__global__ __launch_bounds__(256)
void k_accum_mlp(const u32* __restrict__ es, const int* __restrict__ goff,
                 const float* __restrict__ rel, const float* __restrict__ ctx,
                 const float* __restrict__ w1, const float* __restrict__ b1,
                 const float* __restrict__ w2, const float* __restrict__ b2,
                 const float* __restrict__ strength, float* __restrict__ out,
                 int* __restrict__ alist, int* __restrict__ alcnt,
                 float* __restrict__ wsf, int N) {
    __shared__ float w1e[DD * DD];     // [k][j] = w1[j][k] + w1[j][k+64]
    __shared__ float w2t[DD * DD];     // [k][j] = w2[j][k]
    __shared__ float acc[GSZ * DD];    // 32 KB feature accumulators
    __shared__ int   cntp[GSZ];
    __shared__ int   selfp[GSZ];
    __shared__ float b1s[DD], b2s[DD], ctx_s[DD];
    __shared__ float hbuf[4][DD];

    for (int i = threadIdx.x; i < DD * DD; i += 256) {
        int j = i >> 6, k = i & 63;
        w1e[k * DD + j] = w1[j * 2 * DD + k] + w1[j * 2 * DD + DD + k];
        w2t[k * DD + j] = w2[j * DD + k];
    }
    if (threadIdx.x < DD) {
        b1s[threadIdx.x]   = b1[threadIdx.x];
        b2s[threadIdx.x]   = b2[threadIdx.x];
        ctx_s[threadIdx.x] = ctx[threadIdx.x];
    }
    for (int i = threadIdx.x; i < GSZ * DD; i += 256) acc[i] = 0.f;
    if (threadIdx.x < GSZ) { cntp[threadIdx.x] = 0; selfp[threadIdx.x] = 0; }
    __syncthreads();

    int e0 = goff[blockIdx.x], e1 = goff[blockIdx.x + 1];
    int lane = threadIdx.x & 63;
    int w    = threadIdx.x >> 6;

    // lane-parallel counting
    for (int i = e0 + threadIdx.x; i < e1; i += 256) {
        u32 v = es[i];
        atomicAdd(&cntp[v & (GSZ - 1)], 1);
        if (v >> 31) atomicAdd(&selfp[v & (GSZ - 1)], 1);
    }
    // wave-per-entry accumulation (coalesced 256B rel row per entry)
    int base = e0 + w * 64;
    for (; base + 64 <= e1; base += 256) {
        u32 v = es[base + lane];
        #pragma unroll 8
        for (int j = 0; j < 64; ++j) {
            u32 ve = __shfl(v, j);
            int ln = ve & (GSZ - 1);
            int t  = (int)((ve >> GSH) & 0xFFFFFF);
            float r = rel[t * DD + lane];
            atomicAdd(&acc[ln * DD + lane], r);
        }
    }
    if (base < e1) {                    // partial tail chunk for this wave
        int m = e1 - base;
        u32 v = (lane < m) ? es[base + lane] : 0u;
        for (int j = 0; j < m; ++j) {
            u32 ve = __shfl(v, j);
            int ln = ve & (GSZ - 1);
            int t  = (int)((ve >> GSH) & 0xFFFFFF);
            float r = rel[t * DD + lane];
            atomicAdd(&acc[ln * DD + lane], r);
        }
    }
    __syncthreads();

    float sc = fminf(fmaxf(strength[0], 0.f), 0.3f);
    int nbase = blockIdx.x << GSH;
    for (int ln = w; ln < GSZ; ln += 4) {
        int n = nbase + ln;
        if (n >= N) break;
        int c = cntp[ln];
        if (c == 0) { out[n * DD + lane] = ctx_s[lane]; continue; }
        float inv = 1.f / (float)c;
        float f = acc[ln * DD + lane] * inv;
        if (selfp[ln] == c) {           // only self-loop incidences: branch a
            int p = 0;
            if (lane == 0) p = atomicAdd(alcnt, 1);
            p = __shfl(p, 0);
            if (p < AMAX) {
                wsf[p * DD + lane] = f;
                if (lane == 0) alist[p] = n;
            }
            continue;
        }
        float h = b1s[lane];
        #pragma unroll 8
        for (int k = 0; k < DD; ++k)
            h = fmaf(acc[ln * DD + k] * inv, w1e[k * DD + lane], h);
        h = fmaxf(h, 0.f);
        hbuf[w][lane] = h;              // same-wave write/read: no barrier
        float o = b2s[lane];
        #pragma unroll 8
        for (int k = 0; k < DD; ++k)
            o = fmaf(hbuf[w][k], w2t[k * DD + lane], o);
        out[n * DD + lane] = (1.f - sc) * f + sc * o;
    }
}

// ---------------------------------------------------------------------------
// Rare branch-a nodes: out = (1-s)f + s*mlp_a([f, ctx]); f pre-averaged in wsf.
__global__ __launch_bounds__(256)
void k_brancha(const float* __restrict__ wsf, const float* __restrict__ ctx,
               const float* __restrict__ w1, const float* __restrict__ b1,
               const float* __restrict__ w2, const float* __restrict__ b2,
               const float* __restrict__ strength, float* __restrict__ out,
               const int* __restrict__ alist, const int* __restrict__ alcnt) {
    int count = min(*alcnt, AMAX);
    if (count == 0) return;
    float sc = fminf(fmaxf(strength[0], 0.f), 0.3f);
    int lane = threadIdx.x & 63;
    int w    = threadIdx.x >> 6;
    float c = ctx[lane];
    for (int idx = w; idx < count; idx += 4) {
        int n = alist[idx];
        float f = wsf[idx * DD + lane];
        float h = b1[lane];
        for (int k = 0; k < DD; ++k)
            h = fmaf(__shfl(f, k), w1[lane * 2 * DD + k], h);
        for (int k = 0; k < DD; ++k)
            h = fmaf(__shfl(c, k), w1[lane * 2 * DD + DD + k], h);
        h = fmaxf(h, 0.f);
        float o = b2[lane];
        for (int k = 0; k < DD; ++k)
            o = fmaf(__shfl(h, k), w2[lane * DD + k], o);
        out[n * DD + lane] = (1.f - sc) * f + sc * o;
    }
}

// ---------------------------------------------------------------------------
extern "C" void kernel_launch(void* const* d_in, const int* in_sizes, int n_in,
                              void* d_out, int out_size, void* d_ws, size_t ws_size,
                              hipStream_t stream) {
    const int*   edge_index = (const int*)d_in[0];     // [2, E]
    const int*   etype      = (const int*)d_in[1];     // [E]
    const float* rel        = (const float*)d_in[2];   // [R, 64]
    const float* w1a        = (const float*)d_in[3];
    const float* b1a        = (const float*)d_in[4];
    const float* w2a        = (const float*)d_in[5];
    const float* b2a        = (const float*)d_in[6];
    const float* w1b        = (const float*)d_in[7];
    const float* b1b        = (const float*)d_in[8];
    const float* w2b        = (const float*)d_in[9];
    const float* b2b        = (const float*)d_in[10];
    const float* strength   = (const float*)d_in[11];

    int E = in_sizes[0] / 2;
    int R = in_sizes[2] / DD;
    int N = out_size / DD;
    int G = (N + GSZ - 1) >> GSH;

    float* out = (float*)d_out;
    char*  ws  = (char*)d_ws;

    int*   gcnt  = (int*)ws;                    // G
    int*   alcnt = gcnt + G;                    // 1
    int*   goff  = alcnt + 1;                   // G+1
    int*   gcur  = goff + G + 1;                // G
    float* ctx   = (float*)(gcur + G);          // 64
    int*   alist = (int*)(ctx + DD);            // AMAX
    float* wsf   = (float*)(alist + AMAX);      // AMAX*64
    u32*   es    = (u32*)(wsf + AMAX * DD);     // up to 2E entries

    hipMemsetAsync(gcnt, 0, (size_t)(G + 1) * sizeof(int), stream);

    k_relctx<<<1, 512, 0, stream>>>(rel, R, ctx);

    const int* src = edge_index;
    const int* dst = edge_index + E;
    int nb = (E + TILE - 1) / TILE;

    k_gcount<<<nb, 512, 0, stream>>>(src, dst, gcnt, E, G);
    k_scan<<<1, 1024, 0, stream>>>(gcnt, goff, gcur, G);
    k_gplace<<<nb, 512, 0, stream>>>(src, dst, etype, gcur, es, E, G);

    k_accum_mlp<<<G, 256, 0, stream>>>(es, goff, rel, ctx,
                                       w1b, b1b, w2b, b2b, strength,
                                       out, alist, alcnt, wsf, N);
    k_brancha<<<1, 256, 0, stream>>>(wsf, ctx, w1a, b1a, w2a, b2a, strength,
                                     out, alist, alcnt);
}

// Round 4
// 204.362 us; speedup vs baseline: 7.4722x; 7.4722x over previous
//
#include <hip/hip_runtime.h>

#define DD   64
#define GSH  7            // 128 nodes per group
#define GSZ  128
#define TILE 8192
#define GMAX 1024         // supports N <= 131072
#define AMAX 1024         // branch-a list capacity

typedef unsigned int u32;
typedef unsigned short u16;

// entry (level 1, u32): local(7b) | etype<<7 (9b) | self<<16
// entry (level 2, u16): etype (9b) | self<<9

// ---------------------------------------------------------------------------
__global__ __launch_bounds__(512)
void k_relctx(const float* __restrict__ rel, int R, float* __restrict__ ctx) {
    __shared__ float part[8][DD];
    int d = threadIdx.x & 63;
    int w = threadIdx.x >> 6;
    float s = 0.f;
    for (int r = w; r < R; r += 8) s += rel[r * DD + d];
    part[w][d] = s;
    __syncthreads();
    if (threadIdx.x < DD) {
        float t = 0.f;
        #pragma unroll
        for (int i = 0; i < 8; ++i) t += part[i][threadIdx.x];
        ctx[threadIdx.x] = t / (float)R;
    }
}

// ---------------------------------------------------------------------------
// Pass 1: incidences per 128-node group, LDS histogram per block.
__global__ __launch_bounds__(512)
void k_gcount(const int* __restrict__ src, const int* __restrict__ dst,
              int* __restrict__ gcnt, int E, int G) {
    __shared__ int lcnt[GMAX];
    for (int i = threadIdx.x; i < G; i += 512) lcnt[i] = 0;
    __syncthreads();
    int t0 = blockIdx.x * TILE;
    int t1 = min(t0 + TILE, E);
    for (int i = t0 + threadIdx.x; i < t1; i += 512) {
        int s = src[i], d = dst[i];
        atomicAdd(&lcnt[s >> GSH], 1);
        if (s != d) atomicAdd(&lcnt[d >> GSH], 1);
    }
    __syncthreads();
    for (int g = threadIdx.x; g < G; g += 512) {
        int c = lcnt[g];
        if (c) atomicAdd(&gcnt[g], c);
    }
}

// ---------------------------------------------------------------------------
__global__ __launch_bounds__(1024)
void k_scan(const int* __restrict__ gcnt, int* __restrict__ goff,
            int* __restrict__ gcur, int G) {
    __shared__ int sh[GMAX];
    int t = threadIdx.x;
    int v = (t < G) ? gcnt[t] : 0;
    sh[t] = v;
    __syncthreads();
    for (int d = 1; d < GMAX; d <<= 1) {
        int x = (t >= d) ? sh[t - d] : 0;
        __syncthreads();
        sh[t] += x;
        __syncthreads();
    }
    if (t < G) { int off = sh[t] - v; goff[t] = off; gcur[t] = off; }
    if (t == GMAX - 1) goff[G] = sh[GMAX - 1];
}

// ---------------------------------------------------------------------------
// Pass 2: place entries into coarse group streams (contiguous per-block runs).
__global__ __launch_bounds__(512)
void k_gplace(const int* __restrict__ src, const int* __restrict__ dst,
              const int* __restrict__ etype, int* __restrict__ gcur,
              u32* __restrict__ es, int E, int G) {
    __shared__ int lcnt[GMAX];
    __shared__ int lbase[GMAX];
    for (int i = threadIdx.x; i < G; i += 512) lcnt[i] = 0;
    __syncthreads();
    int t0 = blockIdx.x * TILE;
    int t1 = min(t0 + TILE, E);
    for (int i = t0 + threadIdx.x; i < t1; i += 512) {
        int s = src[i], d = dst[i];
        atomicAdd(&lcnt[s >> GSH], 1);
        if (s != d) atomicAdd(&lcnt[d >> GSH], 1);
    }
    __syncthreads();
    for (int g = threadIdx.x; g < G; g += 512) {
        int c = lcnt[g];
        lbase[g] = c ? atomicAdd(&gcur[g], c) : 0;
        lcnt[g] = 0;
    }
    __syncthreads();
    for (int i = t0 + threadIdx.x; i < t1; i += 512) {
        int s = src[i], d = dst[i];
        u32 t = (u32)etype[i] << GSH;
        if (s != d) {
            int gs = s >> GSH;
            int p = atomicAdd(&lcnt[gs], 1);
            es[lbase[gs] + p] = (u32)(s & (GSZ - 1)) | t;
            int gd = d >> GSH;
            int q = atomicAdd(&lcnt[gd], 1);
            es[lbase[gd] + q] = (u32)(d & (GSZ - 1)) | t;
        } else {
            int gs = s >> GSH;
            int p = atomicAdd(&lcnt[gs], 1);
            es[lbase[gs] + p] = (u32)(s & (GSZ - 1)) | t | 0x10000u;
        }
    }
}

// ---------------------------------------------------------------------------
// Level 2: per-group counting sort -> node-sorted u16 stream (CSR) + noff.
// One block per group; all binning via cheap LDS int atomics on 128 bins.
__global__ __launch_bounds__(256)
void k_sort(const u32* __restrict__ es, const int* __restrict__ goff,
            u16* __restrict__ es2, int* __restrict__ noff, int N, int G) {
    __shared__ int cnt[GSZ];
    __shared__ int pre[GSZ];
    __shared__ int cur[GSZ];
    int g = blockIdx.x;
    int e0 = goff[g], e1 = goff[g + 1];
    if (threadIdx.x < GSZ) cnt[threadIdx.x] = 0;
    __syncthreads();
    for (int i = e0 + threadIdx.x; i < e1; i += 256)
        atomicAdd(&cnt[es[i] & (GSZ - 1)], 1);
    __syncthreads();
    if (threadIdx.x < GSZ) pre[threadIdx.x] = cnt[threadIdx.x];
    __syncthreads();
    for (int d = 1; d < GSZ; d <<= 1) {
        int v = (threadIdx.x < GSZ && threadIdx.x >= d) ? pre[threadIdx.x - d] : 0;
        __syncthreads();
        if (threadIdx.x < GSZ) pre[threadIdx.x] += v;
        __syncthreads();
    }
    if (threadIdx.x < GSZ) {
        int ex = e0 + pre[threadIdx.x] - cnt[threadIdx.x];   // exclusive
        cur[threadIdx.x] = ex;
        int n = (g << GSH) + threadIdx.x;
        if (n < N) noff[n] = ex;
    }
    if (g == G - 1 && threadIdx.x == 0) noff[N] = e1;
    __syncthreads();
    for (int i = e0 + threadIdx.x; i < e1; i += 256) {
        u32 v = es[i];
        int p = atomicAdd(&cur[v & (GSZ - 1)], 1);
        es2[p] = (u16)(v >> GSH);           // etype | self<<9
    }
}

// ---------------------------------------------------------------------------
// Fused CSR gather + branch-b MLP. Wave per node, lane = dim, zero atomics.
__global__ __launch_bounds__(256)
void k_mlp(const u16* __restrict__ es2, const int* __restrict__ noff,
           const float* __restrict__ rel, const float* __restrict__ ctx,
           const float* __restrict__ w1, const float* __restrict__ b1,
           const float* __restrict__ w2, const float* __restrict__ b2,
           const float* __restrict__ strength, float* __restrict__ out,
           int* __restrict__ alist, int* __restrict__ alcnt,
           float* __restrict__ wsf, int N) {
    __shared__ float w1e[DD * DD];   // [k][j] = w1[j][k] + w1[j][k+64]
    __shared__ float w2t[DD * DD];   // [k][j] = w2[j][k]
    __shared__ float b1s[DD], b2s[DD], ctx_s[DD];
    __shared__ float xbuf[4][DD];

    for (int i = threadIdx.x; i < DD * DD; i += 256) {
        int j = i >> 6, k = i & 63;
        w1e[k * DD + j] = w1[j * 2 * DD + k] + w1[j * 2 * DD + DD + k];
        w2t[k * DD + j] = w2[j * DD + k];
    }
    if (threadIdx.x < DD) {
        b1s[threadIdx.x]   = b1[threadIdx.x];
        b2s[threadIdx.x]   = b2[threadIdx.x];
        ctx_s[threadIdx.x] = ctx[threadIdx.x];
    }
    __syncthreads();

    float sc = fminf(fmaxf(strength[0], 0.f), 0.3f);
    int lane = threadIdx.x & 63;
    int w    = threadIdx.x >> 6;
    int gw   = blockIdx.x * 4 + w;
    int nw   = gridDim.x * 4;

    for (int n = gw; n < N; n += nw) {
        int o0 = noff[n], o1 = noff[n + 1];
        int dg = o1 - o0;
        if (dg == 0) { out[n * DD + lane] = ctx_s[lane]; continue; }

        float f = 0.f;
        int selfc = 0;
        int i = o0;
        for (; i + 4 <= o1; i += 4) {
            int e0 = es2[i], e1 = es2[i + 1], e2 = es2[i + 2], e3 = es2[i + 3];
            f += rel[(e0 & 0x1FF) * DD + lane];
            f += rel[(e1 & 0x1FF) * DD + lane];
            f += rel[(e2 & 0x1FF) * DD + lane];
            f += rel[(e3 & 0x1FF) * DD + lane];
            selfc += (e0 >> 9) + (e1 >> 9) + (e2 >> 9) + (e3 >> 9);
        }
        for (; i < o1; ++i) {
            int e = es2[i];
            f += rel[(e & 0x1FF) * DD + lane];
            selfc += e >> 9;
        }
        f /= (float)dg;

        if (selfc == dg) {               // only self-loop incidences: branch a
            int p = 0;
            if (lane == 0) p = atomicAdd(alcnt, 1);
            p = __shfl(p, 0);
            if (p < AMAX) {
                wsf[p * DD + lane] = f;
                if (lane == 0) alist[p] = n;
            }
            continue;
        }
        xbuf[w][lane] = f;               // same-wave LDS broadcast buffer
        float h = b1s[lane];
        #pragma unroll 16
        for (int k = 0; k < DD; ++k)
            h = fmaf(xbuf[w][k], w1e[k * DD + lane], h);
        h = fmaxf(h, 0.f);
        xbuf[w][lane] = h;               // safe: lane's reads complete first
        float o = b2s[lane];
        #pragma unroll 16
        for (int k = 0; k < DD; ++k)
            o = fmaf(xbuf[w][k], w2t[k * DD + lane], o);
        out[n * DD + lane] = (1.f - sc) * f + sc * o;
    }
}

// ---------------------------------------------------------------------------
// Rare branch-a nodes: out = (1-s)f + s*mlp_a([f, ctx]); f pre-averaged in wsf.
__global__ __launch_bounds__(256)
void k_brancha(const float* __restrict__ wsf, const float* __restrict__ ctx,
               const float* __restrict__ w1, const float* __restrict__ b1,
               const float* __restrict__ w2, const float* __restrict__ b2,
               const float* __restrict__ strength, float* __restrict__ out,
               const int* __restrict__ alist, const int* __restrict__ alcnt) {
    int count = min(*alcnt, AMAX);
    if (count == 0) return;
    float sc = fminf(fmaxf(strength[0], 0.f), 0.3f);
    int lane = threadIdx.x & 63;
    int w    = threadIdx.x >> 6;
    float c = ctx[lane];
    for (int idx = w; idx < count; idx += 4) {
        int n = alist[idx];
        float f = wsf[idx * DD + lane];
        float h = b1[lane];
        for (int k = 0; k < DD; ++k)
            h = fmaf(__shfl(f, k), w1[lane * 2 * DD + k], h);
        for (int k = 0; k < DD; ++k)
            h = fmaf(__shfl(c, k), w1[lane * 2 * DD + DD + k], h);
        h = fmaxf(h, 0.f);
        float o = b2[lane];
        for (int k = 0; k < DD; ++k)
            o = fmaf(__shfl(h, k), w2[lane * DD + k], o);
        out[n * DD + lane] = (1.f - sc) * f + sc * o;
    }
}

// ---------------------------------------------------------------------------
extern "C" void kernel_launch(void* const* d_in, const int* in_sizes, int n_in,
                              void* d_out, int out_size, void* d_ws, size_t ws_size,
                              hipStream_t stream) {
    const int*   edge_index = (const int*)d_in[0];     // [2, E]
    const int*   etype      = (const int*)d_in[1];     // [E]
    const float* rel        = (const float*)d_in[2];   // [R, 64]
    const float* w1a        = (const float*)d_in[3];
    const float* b1a        = (const float*)d_in[4];
    const float* w2a        = (const float*)d_in[5];
    const float* b2a        = (const float*)d_in[6];
    const float* w1b        = (const float*)d_in[7];
    const float* b1b        = (const float*)d_in[8];
    const float* w2b        = (const float*)d_in[9];
    const float* b2b        = (const float*)d_in[10];
    const float* strength   = (const float*)d_in[11];

    int E = in_sizes[0] / 2;
    int R = in_sizes[2] / DD;
    int N = out_size / DD;
    int G = (N + GSZ - 1) >> GSH;

    float* out = (float*)d_out;
    char*  ws  = (char*)d_ws;

    int*   gcnt  = (int*)ws;                        // G
    int*   alcnt = gcnt + G;                        // 1
    int*   goff  = alcnt + 1;                       // G+1
    int*   gcur  = goff + G + 1;                    // G
    float* ctx   = (float*)(gcur + G);              // 64
    int*   alist = (int*)(ctx + DD);                // AMAX
    float* wsf   = (float*)(alist + AMAX);          // AMAX*64
    int*   noff  = (int*)(wsf + AMAX * DD);         // N+1
    u32*   es    = (u32*)(noff + N + 1);            // 2E
    u16*   es2   = (u16*)(es + 2 * (size_t)E);      // 2E

    hipMemsetAsync(gcnt, 0, (size_t)(G + 1) * sizeof(int), stream);

    k_relctx<<<1, 512, 0, stream>>>(rel, R, ctx);

    const int* src = edge_index;
    const int* dst = edge_index + E;
    int nb = (E + TILE - 1) / TILE;

    k_gcount<<<nb, 512, 0, stream>>>(src, dst, gcnt, E, G);
    k_scan<<<1, 1024, 0, stream>>>(gcnt, goff, gcur, G);
    k_gplace<<<nb, 512, 0, stream>>>(src, dst, etype, gcur, es, E, G);
    k_sort<<<G, 256, 0, stream>>>(es, goff, es2, noff, N, G);

    k_mlp<<<2048, 256, 0, stream>>>(es2, noff, rel, ctx,
                                    w1b, b1b, w2b, b2b, strength,
                                    out, alist, alcnt, wsf, N);
    k_brancha<<<1, 256, 0, stream>>>(wsf, ctx, w1a, b1a, w2a, b2a, strength,
                                     out, alist, alcnt);
}